// Round 4
// baseline (2652.537 us; speedup 1.0000x reference)
//
#include <hip/hip_runtime.h>

typedef _Float16 half2_t __attribute__((ext_vector_type(2)));
typedef unsigned int u32;
typedef u32 u32x16 __attribute__((ext_vector_type(16)));

#define NW 252   // total windows: 1 initial + 3 warmup + 248 autoregressive

__device__ inline u32 pk(float x, float y) {
  half2_t h; h.x = (_Float16)x; h.y = (_Float16)y;
  return __builtin_bit_cast(u32, h);
}

__device__ inline float fdot2(u32 a, u32 b, float c) {
#if __has_builtin(__builtin_amdgcn_fdot2)
  return __builtin_amdgcn_fdot2(__builtin_bit_cast(half2_t, a),
                                __builtin_bit_cast(half2_t, b), c, false);
#else
  half2_t ah = __builtin_bit_cast(half2_t, a);
  half2_t bh = __builtin_bit_cast(half2_t, b);
  return c + (float)ah.x * (float)bh.x + (float)ah.y * (float)bh.y;
#endif
}

__device__ inline float fast_rcp(float x) {
#if __has_builtin(__builtin_amdgcn_rcpf)
  return __builtin_amdgcn_rcpf(x);
#else
  return 1.0f / x;
#endif
}

__device__ inline float sigf(float x)  { return fast_rcp(1.0f + __expf(-x)); }
__device__ inline float tanh_(float x) { return 1.0f - 2.0f * fast_rcp(__expf(2.0f * x) + 1.0f); }

// butterfly sum over the 4 lanes of a quad (ks = tid&3) via DPP quad_perm (VALU pipe)
__device__ inline float quad_reduce(float v) {
  int x = __builtin_bit_cast(int, v);
  int y = __builtin_amdgcn_update_dpp(0, x, 0xB1, 0xF, 0xF, true); // [1,0,3,2] xor1
  v += __builtin_bit_cast(float, y);
  x = __builtin_bit_cast(int, v);
  y = __builtin_amdgcn_update_dpp(0, x, 0x4E, 0xF, 0xF, true);     // [2,3,0,1] xor2
  v += __builtin_bit_cast(float, y);
  return v;
}

// exchange with lane^4 partner (same ks,j; opposite gate-pair gh)
__device__ inline float swz4(float v) {
  int x = __builtin_bit_cast(int, v);
  int y = __builtin_amdgcn_ds_swizzle(x, 0x101F); // BitMode xor=4, and=0x1F
  return __builtin_bit_cast(float, y);
}

// ---- R4: NO ARRAYS on the hot path. R0-R3 evidence: C-array weights are
// allocas whose loop indices are runtime values until the unroller runs;
// SROA never re-promotes them afterwards -> they lowered to SCRATCH every
// round (VGPR_Count 64-128, WRITE_SIZE 46-64MB == per-thread scratch init,
// immune to launch_bounds/inlining/array-size). ext_vector_type values are
// first-class SSA: they MUST live in VGPRs. Every element access below is a
// literal-constant index, fully macro-expanded.

#define LOADV(sv, basehalf) {                                              \
    const uint4* _p = (const uint4*)(basehalf) + ks * 4;                   \
    uint4 _q0 = _p[0], _q1 = _p[1], _q2 = _p[2], _q3 = _p[3];              \
    sv[0]=_q0.x;  sv[1]=_q0.y;  sv[2]=_q0.z;  sv[3]=_q0.w;                 \
    sv[4]=_q1.x;  sv[5]=_q1.y;  sv[6]=_q1.z;  sv[7]=_q1.w;                 \
    sv[8]=_q2.x;  sv[9]=_q2.y;  sv[10]=_q2.z; sv[11]=_q2.w;                \
    sv[12]=_q3.x; sv[13]=_q3.y; sv[14]=_q3.z; sv[15]=_q3.w; }

#define PACKV(vec, baseptr) {                                              \
    const float4* _pp = (const float4*)(baseptr);                          \
    float4 _f0=_pp[0],_f1=_pp[1],_f2=_pp[2],_f3=_pp[3];                    \
    float4 _f4=_pp[4],_f5=_pp[5],_f6=_pp[6],_f7=_pp[7];                    \
    vec[0]=pk(_f0.x,_f0.y);   vec[1]=pk(_f0.z,_f0.w);                      \
    vec[2]=pk(_f1.x,_f1.y);   vec[3]=pk(_f1.z,_f1.w);                      \
    vec[4]=pk(_f2.x,_f2.y);   vec[5]=pk(_f2.z,_f2.w);                      \
    vec[6]=pk(_f3.x,_f3.y);   vec[7]=pk(_f3.z,_f3.w);                      \
    vec[8]=pk(_f4.x,_f4.y);   vec[9]=pk(_f4.z,_f4.w);                      \
    vec[10]=pk(_f5.x,_f5.y);  vec[11]=pk(_f5.z,_f5.w);                     \
    vec[12]=pk(_f6.x,_f6.y);  vec[13]=pk(_f6.z,_f6.w);                     \
    vec[14]=pk(_f7.x,_f7.y);  vec[15]=pk(_f7.z,_f7.w); }

#define DOT16(a0, a1, wlo, whi, sv) {                                      \
    a0 = fdot2(wlo[0],  sv[0],  a0);  a1 = fdot2(whi[0],  sv[0],  a1);     \
    a0 = fdot2(wlo[1],  sv[1],  a0);  a1 = fdot2(whi[1],  sv[1],  a1);     \
    a0 = fdot2(wlo[2],  sv[2],  a0);  a1 = fdot2(whi[2],  sv[2],  a1);     \
    a0 = fdot2(wlo[3],  sv[3],  a0);  a1 = fdot2(whi[3],  sv[3],  a1);     \
    a0 = fdot2(wlo[4],  sv[4],  a0);  a1 = fdot2(whi[4],  sv[4],  a1);     \
    a0 = fdot2(wlo[5],  sv[5],  a0);  a1 = fdot2(whi[5],  sv[5],  a1);     \
    a0 = fdot2(wlo[6],  sv[6],  a0);  a1 = fdot2(whi[6],  sv[6],  a1);     \
    a0 = fdot2(wlo[7],  sv[7],  a0);  a1 = fdot2(whi[7],  sv[7],  a1);     \
    a0 = fdot2(wlo[8],  sv[8],  a0);  a1 = fdot2(whi[8],  sv[8],  a1);     \
    a0 = fdot2(wlo[9],  sv[9],  a0);  a1 = fdot2(whi[9],  sv[9],  a1);     \
    a0 = fdot2(wlo[10], sv[10], a0);  a1 = fdot2(whi[10], sv[10], a1);     \
    a0 = fdot2(wlo[11], sv[11], a0);  a1 = fdot2(whi[11], sv[11], a1);     \
    a0 = fdot2(wlo[12], sv[12], a0);  a1 = fdot2(whi[12], sv[12], a1);     \
    a0 = fdot2(wlo[13], sv[13], a0);  a1 = fdot2(whi[13], sv[13], a1);     \
    a0 = fdot2(wlo[14], sv[14], a0);  a1 = fdot2(whi[14], sv[14], a1);     \
    a0 = fdot2(wlo[15], sv[15], a0);  a1 = fdot2(whi[15], sv[15], a1); }

// Gate-split (verified R3): 1024 threads = j(128) x gh(2) x ks(4).
// gh0 holds gate rows {i,g}, gh1 holds {f,o}. Cell update does one
// cross-gh exchange via ds_swizzle xor4: gh0 sends A=sig(i)*tanh(g),
// gh1 sends F=sig(f); both compute identical c. h finalized on gh1.

#define L0STEP(w_, t_, p_) {                                               \
    float x0, x1, x2;                                                      \
    if ((w_) < 4) {                                                        \
      if ((w_) == 0 || (t_) < 3) {                                         \
        const float* r_ = &trajS[((w_) + (t_)) * 3];                       \
        x0 = r_[0]; x1 = r_[1]; x2 = r_[2];                                \
      } else {                       /* warmup last row: [ctrl, p_{w-1}] */ \
        x0 = trajS[(4 + (w_)) * 3];                                        \
        x1 = preds[((w_) - 1) * 2];                                        \
        x2 = preds[((w_) - 1) * 2 + 1];                                    \
      }                                                                    \
    } else {                         /* AR: [p0, p1, ctrl] */              \
      const int s_ = (w_) - 4;                                             \
      x0 = preds[(s_ + (t_)) * 2];                                         \
      x1 = preds[(s_ + (t_)) * 2 + 1];                                     \
      x2 = trajS[((w_) + (t_)) * 3];                                       \
    }                                                                      \
    const bool lead_ = (ks == 0);                                          \
    float a0_ = b0lo + w0a0*x0 + w0a1*x1 + w0a2*x2;                        \
    float a1_ = b0hi + w0b0*x0 + w0b1*x1 + w0b2*x2;                        \
    float acc0 = lead_ ? a0_ : 0.f, acc1 = lead_ ? a1_ : 0.f;              \
    if ((t_) > 0) {                                                        \
      u32x16 su;                                                           \
      LOADV(su, h0buf[p_]);                                                \
      DOT16(acc0, acc1, wA0, wA1, su);                                     \
    }                                                                      \
    acc0 = quad_reduce(acc0); acc1 = quad_reduce(acc1);                    \
    float sg_ = sigf(acc0);           /* gh0: sig(i)   gh1: sig(f) */      \
    float tg_ = tanh_(acc1);          /* gh0: tanh(g) */                   \
    float og_ = sigf(acc1);           /* gh1: sig(o)  */                   \
    float snd_ = gh ? sg_ : sg_ * tg_;                                     \
    float rcv_ = swz4(snd_);                                               \
    float A_ = gh ? rcv_ : snd_;                                           \
    float F_ = gh ? snd_ : rcv_;                                           \
    float cp_ = (t_) ? c0 : 0.f;                                           \
    c0  = F_ * cp_ + A_;                                                   \
    h0f = og_ * tanh_(c0);            /* valid on gh1 */                   \
    if (lead_ && gh) h0buf[(p_) ^ 1][j] = (_Float16)h0f;                   \
  }

#define L1STEP(t_, p_) {                                                   \
    const bool lead_ = (ks == 0);                                          \
    float acc0 = lead_ ? b1lo : 0.f, acc1 = lead_ ? b1hi : 0.f;            \
    {                                                                      \
      u32x16 sy;                                                           \
      LOADV(sy, h0buf[p_]);          /* y0[t] = h0[t] */                   \
      DOT16(acc0, acc1, wB0, wB1, sy);                                     \
    }                                                                      \
    if ((t_) > 0) {                                                        \
      u32x16 sh;                                                           \
      LOADV(sh, h1buf[p_]);                                                \
      DOT16(acc0, acc1, wC0, wC1, sh);                                     \
    }                                                                      \
    acc0 = quad_reduce(acc0); acc1 = quad_reduce(acc1);                    \
    float sg_ = sigf(acc0);                                                \
    float tg_ = tanh_(acc1);                                               \
    float og_ = sigf(acc1);                                                \
    float snd_ = gh ? sg_ : sg_ * tg_;                                     \
    float rcv_ = swz4(snd_);                                               \
    float A_ = gh ? rcv_ : snd_;                                           \
    float F_ = gh ? snd_ : rcv_;                                           \
    float cp_ = (t_) ? c1 : 0.f;                                           \
    c1  = F_ * cp_ + A_;                                                   \
    h1f = og_ * tanh_(c1);            /* valid on gh1 */                   \
    if (lead_ && gh) {                                                     \
      h1buf[(p_) ^ 1][j] = (_Float16)h1f;                                  \
      if ((t_) == 3) sh_h1f[j] = h1f;  /* f32 copy for the head */         \
    }                                                                      \
  }

#define HD(w_) {                                                           \
    if (tid < 8) {                                                         \
      const int d_ = tid >> 2;         /* ks = tid&3 splits K */           \
      const float* wrow_ = &sh_Wl[d_ * 128 + ks * 32];                     \
      const float* hrow_ = &sh_h1f[ks * 32];                               \
      float s_ = 0.f;                                                      \
      _Pragma("unroll")                                                    \
      for (int m = 0; m < 32; ++m) s_ = fmaf(wrow_[m], hrow_[m], s_);      \
      s_ = quad_reduce(s_);                                                \
      if (ks == 0) {                                                       \
        float base_ = ((w_) < 4) ? trajS[(3 + (w_)) * 3 + 1 + d_]          \
                                 : preds[((w_) - 1) * 2 + d_];             \
        preds[(w_) * 2 + d_] = base_ + s_ + blv;                           \
      }                                                                    \
    }                                                                      \
  }

// 1024 threads, one block per CU (grid=128 on 256 CUs), 16 waves = 4/SIMD.
__global__ __launch_bounds__(1024, 1) void lstm_roll(
    const float* __restrict__ traj,
    const float* __restrict__ Wih0, const float* __restrict__ Whh0,
    const float* __restrict__ bih0, const float* __restrict__ bhh0,
    const float* __restrict__ Wih1, const float* __restrict__ Whh1,
    const float* __restrict__ bih1, const float* __restrict__ bhh1,
    const float* __restrict__ Wl,   const float* __restrict__ bl,
    float* __restrict__ out)
{
  const int b   = blockIdx.x;
  const int B   = gridDim.x;
  const int tid = threadIdx.x;
  const int ks  = tid & 3;          // k-slice 0..3 (32 k's each)
  const int gh  = (tid >> 2) & 1;   // gate-pair: 0 -> {i,g}, 1 -> {f,o}
  const int j   = tid >> 3;         // hidden index 0..127

  __shared__ __align__(16) _Float16 h0buf[2][128];  // parity ping-pong
  __shared__ __align__(16) _Float16 h1buf[2][128];
  __shared__ float sh_h1f[128];      // f32 h1[3] for the head
  __shared__ float sh_Wl[256];
  __shared__ float trajS[256 * 3];
  __shared__ float preds[NW * 2];

  for (int i = tid; i < 768; i += 1024) trajS[i] = traj[b * 768 + i];
  if (tid < 256) sh_Wl[tid] = Wl[tid];
  float blv = 0.0f;
  if (tid < 8) blv = bl[tid >> 2];

  // ---- register-resident weights: 2 gate rows x 32-k slice, f16 packed ----
  // NAMED ext_vectors (SSA), not arrays (allocas) — see R4 note above.
  u32x16 wA0, wA1, wB0, wB1, wC0, wC1;     // Whh0, Wih1, Whh1 (lo=gate gh, hi=gate gh+2)
  float b0lo, b0hi, b1lo, b1hi;
  float w0a0, w0a1, w0a2, w0b0, w0b1, w0b2;
  {
    const int row0 = gh * 128 + j;         // gate gh     (gh0: i, gh1: f)
    const int row1 = (gh + 2) * 128 + j;   // gate gh+2   (gh0: g, gh1: o)
    b0lo = bih0[row0] + bhh0[row0];
    b0hi = bih0[row1] + bhh0[row1];
    b1lo = bih1[row0] + bhh1[row0];
    b1hi = bih1[row1] + bhh1[row1];
    w0a0 = Wih0[row0*3+0]; w0a1 = Wih0[row0*3+1]; w0a2 = Wih0[row0*3+2];
    w0b0 = Wih0[row1*3+0]; w0b1 = Wih0[row1*3+1]; w0b2 = Wih0[row1*3+2];
    PACKV(wA0, Whh0 + row0 * 128 + ks * 32);
    PACKV(wA1, Whh0 + row1 * 128 + ks * 32);
    PACKV(wB0, Wih1 + row0 * 128 + ks * 32);
    PACKV(wB1, Wih1 + row1 * 128 + ks * 32);
    PACKV(wC0, Whh1 + row0 * 128 + ks * 32);
    PACKV(wC1, Whh1 + row1 * 128 + ks * 32);
  }

  float c0 = 0.f, c1 = 0.f, h0f = 0.f, h1f = 0.f;

  __syncthreads();

  int p = 0;
  // prologue: L0[0] of window 0 (no h-dependency)
  L0STEP(0, 0, p);
  __syncthreads(); p ^= 1;

#pragma unroll 1
  for (int w = 0; w < NW; ++w) {
    // s0: head(w-1) || L0[1](w) || L1[0](w)
    if (w > 0) HD(w - 1);
    L0STEP(w, 1, p);
    L1STEP(0, p);
    __syncthreads(); p ^= 1;
    // s1: L0[2](w) || L1[1](w)
    L0STEP(w, 2, p);
    L1STEP(1, p);
    __syncthreads(); p ^= 1;
    // s2: L0[3](w) || L1[2](w)   (preds[w-1] ready since s0)
    L0STEP(w, 3, p);
    L1STEP(2, p);
    __syncthreads(); p ^= 1;
    // s3: L1[3](w) || L0[0](w+1)
    L1STEP(3, p);
    if (w < NW - 1) L0STEP(w + 1, 0, p);
    __syncthreads(); p ^= 1;
  }

  // epilogue: head of the last window
  HD(NW - 1);
  __syncthreads();

  // ================= outputs =================
  for (int i = tid; i < NW * 2; i += 1024) out[b * (NW * 2) + i] = preds[i];
  if (ks == 0 && gh == 1) {           // h0f/h1f finalized on gh1 lanes
    const int oh = B * NW * 2;
    const int oc = oh + 2 * B * 128;
    out[oh +            b * 128 + j] = h0f;
    out[oh + B * 128 +  b * 128 + j] = h1f;
    out[oc +            b * 128 + j] = c0;
    out[oc + B * 128 +  b * 128 + j] = c1;
  }
}

extern "C" void kernel_launch(void* const* d_in, const int* in_sizes, int n_in,
                              void* d_out, int out_size, void* d_ws, size_t ws_size,
                              hipStream_t stream) {
  const float* traj = (const float*)d_in[0];
  const float* Wih0 = (const float*)d_in[1];
  const float* Whh0 = (const float*)d_in[2];
  const float* bih0 = (const float*)d_in[3];
  const float* bhh0 = (const float*)d_in[4];
  const float* Wih1 = (const float*)d_in[5];
  const float* Whh1 = (const float*)d_in[6];
  const float* bih1 = (const float*)d_in[7];
  const float* bhh1 = (const float*)d_in[8];
  const float* Wl   = (const float*)d_in[9];
  const float* bl   = (const float*)d_in[10];

  const int B = in_sizes[0] / (256 * 3);   // 128
  hipLaunchKernelGGL(lstm_roll, dim3(B), dim3(1024), 0, stream,
                     traj, Wih0, Whh0, bih0, bhh0, Wih1, Whh1, bih1, bhh1,
                     Wl, bl, (float*)d_out);
}

// Round 5
// 1333.249 us; speedup vs baseline: 1.9895x; 1.9895x over previous
//
#include <hip/hip_runtime.h>

typedef _Float16 half2_t __attribute__((ext_vector_type(2)));
typedef unsigned int u32;
typedef u32 u32x16 __attribute__((ext_vector_type(16)));

#define NW 252   // total windows: 1 initial + 3 warmup + 248 autoregressive

__device__ inline u32 pk(float x, float y) {
  half2_t h; h.x = (_Float16)x; h.y = (_Float16)y;
  return __builtin_bit_cast(u32, h);
}

__device__ inline float fdot2(u32 a, u32 b, float c) {
#if __has_builtin(__builtin_amdgcn_fdot2)
  return __builtin_amdgcn_fdot2(__builtin_bit_cast(half2_t, a),
                                __builtin_bit_cast(half2_t, b), c, false);
#else
  half2_t ah = __builtin_bit_cast(half2_t, a);
  half2_t bh = __builtin_bit_cast(half2_t, b);
  return c + (float)ah.x * (float)bh.x + (float)ah.y * (float)bh.y;
#endif
}

__device__ inline float fast_rcp(float x) {
#if __has_builtin(__builtin_amdgcn_rcpf)
  return __builtin_amdgcn_rcpf(x);
#else
  return 1.0f / x;
#endif
}

__device__ inline float sigf(float x)  { return fast_rcp(1.0f + __expf(-x)); }
__device__ inline float tanh_(float x) { return 1.0f - 2.0f * fast_rcp(__expf(2.0f * x) + 1.0f); }

// butterfly sum over the 4 lanes of a quad (ks = tid&3) via DPP quad_perm (VALU pipe)
__device__ inline float quad_reduce(float v) {
  int x = __builtin_bit_cast(int, v);
  int y = __builtin_amdgcn_update_dpp(0, x, 0xB1, 0xF, 0xF, true); // [1,0,3,2] xor1
  v += __builtin_bit_cast(float, y);
  x = __builtin_bit_cast(int, v);
  y = __builtin_amdgcn_update_dpp(0, x, 0x4E, 0xF, 0xF, true);     // [2,3,0,1] xor2
  v += __builtin_bit_cast(float, y);
  return v;
}

// ---- R5 diagnosis: the spill was the ALLOCATOR'S occupancy heuristic, not
// SROA. Evidence: VGPR_Count == 512-reg-SIMD-pool / (waves needed for TWO
// blocks/CU) in every round (512thr->128, 1024thr->64), regardless of
// launch_bounds/lambdas/macros/ext_vectors. __launch_bounds__'s 2nd arg only
// RAISES the budget floor; it never lowers the occupancy TARGET, so the RA
// kept spilling ~200 regs/thread to scratch (WRITE_SIZE 46-64MB) to keep a
// 2-blocks/CU target that our 128-block grid on 256 CUs never uses.
// Fix: amdgpu_waves_per_eu(2,2) pins min=max=2 waves/SIMD -> budget 256
// VGPRs/wave, and the RA has no incentive to spill below it.

#define LOADV(sv, basehalf) {                                              \
    const uint4* _p = (const uint4*)(basehalf) + ks * 4;                   \
    uint4 _q0 = _p[0], _q1 = _p[1], _q2 = _p[2], _q3 = _p[3];              \
    sv[0]=_q0.x;  sv[1]=_q0.y;  sv[2]=_q0.z;  sv[3]=_q0.w;                 \
    sv[4]=_q1.x;  sv[5]=_q1.y;  sv[6]=_q1.z;  sv[7]=_q1.w;                 \
    sv[8]=_q2.x;  sv[9]=_q2.y;  sv[10]=_q2.z; sv[11]=_q2.w;                \
    sv[12]=_q3.x; sv[13]=_q3.y; sv[14]=_q3.z; sv[15]=_q3.w; }

#define PACKV(vec, baseptr) {                                              \
    const float4* _pp = (const float4*)(baseptr);                          \
    float4 _f0=_pp[0],_f1=_pp[1],_f2=_pp[2],_f3=_pp[3];                    \
    float4 _f4=_pp[4],_f5=_pp[5],_f6=_pp[6],_f7=_pp[7];                    \
    vec[0]=pk(_f0.x,_f0.y);   vec[1]=pk(_f0.z,_f0.w);                      \
    vec[2]=pk(_f1.x,_f1.y);   vec[3]=pk(_f1.z,_f1.w);                      \
    vec[4]=pk(_f2.x,_f2.y);   vec[5]=pk(_f2.z,_f2.w);                      \
    vec[6]=pk(_f3.x,_f3.y);   vec[7]=pk(_f3.z,_f3.w);                      \
    vec[8]=pk(_f4.x,_f4.y);   vec[9]=pk(_f4.z,_f4.w);                      \
    vec[10]=pk(_f5.x,_f5.y);  vec[11]=pk(_f5.z,_f5.w);                     \
    vec[12]=pk(_f6.x,_f6.y);  vec[13]=pk(_f6.z,_f6.w);                     \
    vec[14]=pk(_f7.x,_f7.y);  vec[15]=pk(_f7.z,_f7.w); }

#define DOT16x4(a0, a1, a2, a3, w0, w1, w2, w3, sv) {                      \
    a0=fdot2(w0[0],sv[0],a0);  a1=fdot2(w1[0],sv[0],a1);                   \
    a2=fdot2(w2[0],sv[0],a2);  a3=fdot2(w3[0],sv[0],a3);                   \
    a0=fdot2(w0[1],sv[1],a0);  a1=fdot2(w1[1],sv[1],a1);                   \
    a2=fdot2(w2[1],sv[1],a2);  a3=fdot2(w3[1],sv[1],a3);                   \
    a0=fdot2(w0[2],sv[2],a0);  a1=fdot2(w1[2],sv[2],a1);                   \
    a2=fdot2(w2[2],sv[2],a2);  a3=fdot2(w3[2],sv[2],a3);                   \
    a0=fdot2(w0[3],sv[3],a0);  a1=fdot2(w1[3],sv[3],a1);                   \
    a2=fdot2(w2[3],sv[3],a2);  a3=fdot2(w3[3],sv[3],a3);                   \
    a0=fdot2(w0[4],sv[4],a0);  a1=fdot2(w1[4],sv[4],a1);                   \
    a2=fdot2(w2[4],sv[4],a2);  a3=fdot2(w3[4],sv[4],a3);                   \
    a0=fdot2(w0[5],sv[5],a0);  a1=fdot2(w1[5],sv[5],a1);                   \
    a2=fdot2(w2[5],sv[5],a2);  a3=fdot2(w3[5],sv[5],a3);                   \
    a0=fdot2(w0[6],sv[6],a0);  a1=fdot2(w1[6],sv[6],a1);                   \
    a2=fdot2(w2[6],sv[6],a2);  a3=fdot2(w3[6],sv[6],a3);                   \
    a0=fdot2(w0[7],sv[7],a0);  a1=fdot2(w1[7],sv[7],a1);                   \
    a2=fdot2(w2[7],sv[7],a2);  a3=fdot2(w3[7],sv[7],a3);                   \
    a0=fdot2(w0[8],sv[8],a0);  a1=fdot2(w1[8],sv[8],a1);                   \
    a2=fdot2(w2[8],sv[8],a2);  a3=fdot2(w3[8],sv[8],a3);                   \
    a0=fdot2(w0[9],sv[9],a0);  a1=fdot2(w1[9],sv[9],a1);                   \
    a2=fdot2(w2[9],sv[9],a2);  a3=fdot2(w3[9],sv[9],a3);                   \
    a0=fdot2(w0[10],sv[10],a0); a1=fdot2(w1[10],sv[10],a1);                \
    a2=fdot2(w2[10],sv[10],a2); a3=fdot2(w3[10],sv[10],a3);                \
    a0=fdot2(w0[11],sv[11],a0); a1=fdot2(w1[11],sv[11],a1);                \
    a2=fdot2(w2[11],sv[11],a2); a3=fdot2(w3[11],sv[11],a3);                \
    a0=fdot2(w0[12],sv[12],a0); a1=fdot2(w1[12],sv[12],a1);                \
    a2=fdot2(w2[12],sv[12],a2); a3=fdot2(w3[12],sv[12],a3);                \
    a0=fdot2(w0[13],sv[13],a0); a1=fdot2(w1[13],sv[13],a1);                \
    a2=fdot2(w2[13],sv[13],a2); a3=fdot2(w3[13],sv[13],a3);                \
    a0=fdot2(w0[14],sv[14],a0); a1=fdot2(w1[14],sv[14],a1);                \
    a2=fdot2(w2[14],sv[14],a2); a3=fdot2(w3[14],sv[14],a3);                \
    a0=fdot2(w0[15],sv[15],a0); a1=fdot2(w1[15],sv[15],a1);                \
    a2=fdot2(w2[15],sv[15],a2); a3=fdot2(w3[15],sv[15],a3); }

#define L0STEP(w_, t_, p_) {                                               \
    float x0, x1, x2;                                                      \
    if ((w_) < 4) {                                                        \
      if ((w_) == 0 || (t_) < 3) {                                         \
        const float* r_ = &trajS[((w_) + (t_)) * 3];                       \
        x0 = r_[0]; x1 = r_[1]; x2 = r_[2];                                \
      } else {                       /* warmup last row: [ctrl, p_{w-1}] */ \
        x0 = trajS[(4 + (w_)) * 3];                                        \
        x1 = preds[((w_) - 1) * 2];                                        \
        x2 = preds[((w_) - 1) * 2 + 1];                                    \
      }                                                                    \
    } else {                         /* AR: [p0, p1, ctrl] */              \
      const int s_ = (w_) - 4;                                             \
      x0 = preds[(s_ + (t_)) * 2];                                         \
      x1 = preds[(s_ + (t_)) * 2 + 1];                                     \
      x2 = trajS[((w_) + (t_)) * 3];                                       \
    }                                                                      \
    const bool lead_ = (ks == 0);                                          \
    float a0_ = b0r0 + w0r0*x0 + w0r1 *x1 + w0r2 *x2;                      \
    float a1_ = b0r1 + w0r3*x0 + w0r4 *x1 + w0r5 *x2;                      \
    float a2_ = b0r2 + w0r6*x0 + w0r7 *x1 + w0r8 *x2;                      \
    float a3_ = b0r3 + w0r9*x0 + w0r10*x1 + w0r11*x2;                      \
    float acc0 = lead_ ? a0_ : 0.f, acc1 = lead_ ? a1_ : 0.f;              \
    float acc2 = lead_ ? a2_ : 0.f, acc3 = lead_ ? a3_ : 0.f;              \
    if ((t_) > 0) {                                                        \
      u32x16 su;                                                           \
      LOADV(su, h0buf[p_]);                                                \
      DOT16x4(acc0, acc1, acc2, acc3, wAg0, wAg1, wAg2, wAg3, su);         \
    }                                                                      \
    acc0 = quad_reduce(acc0); acc1 = quad_reduce(acc1);                    \
    acc2 = quad_reduce(acc2); acc3 = quad_reduce(acc3);                    \
    float ig_ = sigf(acc0), fg_ = sigf(acc1);                              \
    float gg_ = tanh_(acc2), og_ = sigf(acc3);                             \
    float cp_ = (t_) ? c0 : 0.f;                                           \
    c0  = fg_ * cp_ + ig_ * gg_;                                           \
    h0f = og_ * tanh_(c0);                                                 \
    if (lead_) h0buf[(p_) ^ 1][j] = (_Float16)h0f;                         \
  }

#define L1STEP(t_, p_) {                                                   \
    const bool lead_ = (ks == 0);                                          \
    float acc0 = lead_ ? b1r0 : 0.f, acc1 = lead_ ? b1r1 : 0.f;            \
    float acc2 = lead_ ? b1r2 : 0.f, acc3 = lead_ ? b1r3 : 0.f;            \
    {                                                                      \
      u32x16 sy;                                                           \
      LOADV(sy, h0buf[p_]);          /* y0[t] = h0[t] */                   \
      DOT16x4(acc0, acc1, acc2, acc3, wBg0, wBg1, wBg2, wBg3, sy);         \
    }                                                                      \
    if ((t_) > 0) {                                                        \
      u32x16 sh;                                                           \
      LOADV(sh, h1buf[p_]);                                                \
      DOT16x4(acc0, acc1, acc2, acc3, wCg0, wCg1, wCg2, wCg3, sh);         \
    }                                                                      \
    acc0 = quad_reduce(acc0); acc1 = quad_reduce(acc1);                    \
    acc2 = quad_reduce(acc2); acc3 = quad_reduce(acc3);                    \
    float ig_ = sigf(acc0), fg_ = sigf(acc1);                              \
    float gg_ = tanh_(acc2), og_ = sigf(acc3);                             \
    float cp_ = (t_) ? c1 : 0.f;                                           \
    c1  = fg_ * cp_ + ig_ * gg_;                                           \
    h1f = og_ * tanh_(c1);                                                 \
    if (lead_) {                                                           \
      h1buf[(p_) ^ 1][j] = (_Float16)h1f;                                  \
      if ((t_) == 3) sh_h1f[j] = h1f;  /* f32 copy for the head */         \
    }                                                                      \
  }

#define HD(w_) {                                                           \
    if (tid < 8) {                                                         \
      const int d_ = tid >> 2;         /* ks = tid&3 splits K */           \
      const float* wrow_ = &sh_Wl[d_ * 128 + ks * 32];                     \
      const float* hrow_ = &sh_h1f[ks * 32];                               \
      float s_ = 0.f;                                                      \
      _Pragma("unroll")                                                    \
      for (int m = 0; m < 32; ++m) s_ = fmaf(wrow_[m], hrow_[m], s_);      \
      s_ = quad_reduce(s_);                                                \
      if (ks == 0) {                                                       \
        float base_ = ((w_) < 4) ? trajS[(3 + (w_)) * 3 + 1 + d_]          \
                                 : preds[((w_) - 1) * 2 + d_];             \
        preds[(w_) * 2 + d_] = base_ + s_ + blv;                           \
      }                                                                    \
    }                                                                      \
  }

#define SETUPG(g_, b0_, b1_, wx0_, wx1_, wx2_, wAv_, wBv_, wCv_) {         \
    const int row_ = (g_) * 128 + j;                                       \
    b0_ = bih0[row_] + bhh0[row_];                                         \
    b1_ = bih1[row_] + bhh1[row_];                                         \
    wx0_ = Wih0[row_*3+0]; wx1_ = Wih0[row_*3+1]; wx2_ = Wih0[row_*3+2];   \
    PACKV(wAv_, Whh0 + row_ * 128 + ks * 32);                              \
    PACKV(wBv_, Wih1 + row_ * 128 + ks * 32);                              \
    PACKV(wCv_, Whh1 + row_ * 128 + ks * 32); }

// 512 threads (8 waves = 2/SIMD), one block per CU (grid=128 on 256 CUs).
// amdgpu_waves_per_eu(2,2): pin occupancy target = budget = 256 VGPR/wave.
__global__
__attribute__((amdgpu_waves_per_eu(2, 2)))
__launch_bounds__(512)
void lstm_roll(
    const float* __restrict__ traj,
    const float* __restrict__ Wih0, const float* __restrict__ Whh0,
    const float* __restrict__ bih0, const float* __restrict__ bhh0,
    const float* __restrict__ Wih1, const float* __restrict__ Whh1,
    const float* __restrict__ bih1, const float* __restrict__ bhh1,
    const float* __restrict__ Wl,   const float* __restrict__ bl,
    float* __restrict__ out)
{
  const int b   = blockIdx.x;
  const int B   = gridDim.x;
  const int tid = threadIdx.x;
  const int j   = tid >> 2;   // hidden index 0..127
  const int ks  = tid & 3;    // k-slice 0..3 (32 k's each)

  __shared__ __align__(16) _Float16 h0buf[2][128];  // parity ping-pong
  __shared__ __align__(16) _Float16 h1buf[2][128];
  __shared__ float sh_h1f[128];      // f32 h1[3] for the head
  __shared__ float sh_Wl[256];
  __shared__ float trajS[256 * 3];
  __shared__ float preds[NW * 2];

  for (int i = tid; i < 768; i += 512) trajS[i] = traj[b * 768 + i];
  if (tid < 256) sh_Wl[tid] = Wl[tid];
  float blv = 0.0f;
  if (tid < 8) blv = bl[tid >> 2];

  // ---- register-resident weights: 4 gate rows x 32-k slice, f16 packed ----
  // NAMED ext_vectors (SSA) + named scalars; no allocas anywhere hot.
  u32x16 wAg0, wAg1, wAg2, wAg3;   // Whh0 rows for gates i,f,g,o
  u32x16 wBg0, wBg1, wBg2, wBg3;   // Wih1
  u32x16 wCg0, wCg1, wCg2, wCg3;   // Whh1
  float b0r0, b0r1, b0r2, b0r3, b1r0, b1r1, b1r2, b1r3;
  float w0r0, w0r1, w0r2, w0r3, w0r4, w0r5, w0r6, w0r7, w0r8, w0r9, w0r10, w0r11;
  SETUPG(0, b0r0, b1r0, w0r0, w0r1, w0r2,  wAg0, wBg0, wCg0);
  SETUPG(1, b0r1, b1r1, w0r3, w0r4, w0r5,  wAg1, wBg1, wCg1);
  SETUPG(2, b0r2, b1r2, w0r6, w0r7, w0r8,  wAg2, wBg2, wCg2);
  SETUPG(3, b0r3, b1r3, w0r9, w0r10, w0r11, wAg3, wBg3, wCg3);

  float c0 = 0.f, c1 = 0.f, h0f = 0.f, h1f = 0.f;

  __syncthreads();

  int p = 0;
  // prologue: L0[0] of window 0 (no h-dependency)
  L0STEP(0, 0, p);
  __syncthreads(); p ^= 1;

#pragma unroll 1
  for (int w = 0; w < NW; ++w) {
    // s0: head(w-1) || L0[1](w) || L1[0](w)
    if (w > 0) HD(w - 1);
    L0STEP(w, 1, p);
    L1STEP(0, p);
    __syncthreads(); p ^= 1;
    // s1: L0[2](w) || L1[1](w)
    L0STEP(w, 2, p);
    L1STEP(1, p);
    __syncthreads(); p ^= 1;
    // s2: L0[3](w) || L1[2](w)   (preds[w-1] ready since s0)
    L0STEP(w, 3, p);
    L1STEP(2, p);
    __syncthreads(); p ^= 1;
    // s3: L1[3](w) || L0[0](w+1)
    L1STEP(3, p);
    if (w < NW - 1) L0STEP(w + 1, 0, p);
    __syncthreads(); p ^= 1;
  }

  // epilogue: head of the last window
  HD(NW - 1);
  __syncthreads();

  // ================= outputs =================
  for (int i = tid; i < NW * 2; i += 512) out[b * (NW * 2) + i] = preds[i];
  if (ks == 0) {
    const int oh = B * NW * 2;
    const int oc = oh + 2 * B * 128;
    out[oh +            b * 128 + j] = h0f;
    out[oh + B * 128 +  b * 128 + j] = h1f;
    out[oc +            b * 128 + j] = c0;
    out[oc + B * 128 +  b * 128 + j] = c1;
  }
}

extern "C" void kernel_launch(void* const* d_in, const int* in_sizes, int n_in,
                              void* d_out, int out_size, void* d_ws, size_t ws_size,
                              hipStream_t stream) {
  const float* traj = (const float*)d_in[0];
  const float* Wih0 = (const float*)d_in[1];
  const float* Whh0 = (const float*)d_in[2];
  const float* bih0 = (const float*)d_in[3];
  const float* bhh0 = (const float*)d_in[4];
  const float* Wih1 = (const float*)d_in[5];
  const float* Whh1 = (const float*)d_in[6];
  const float* bih1 = (const float*)d_in[7];
  const float* bhh1 = (const float*)d_in[8];
  const float* Wl   = (const float*)d_in[9];
  const float* bl   = (const float*)d_in[10];

  const int B = in_sizes[0] / (256 * 3);   // 128
  hipLaunchKernelGGL(lstm_roll, dim3(B), dim3(512), 0, stream,
                     traj, Wih0, Whh0, bih0, bhh0, Wih1, Whh1, bih1, bhh1,
                     Wl, bl, (float*)d_out);
}